// Round 11
// baseline (488.396 us; speedup 1.0000x reference)
//
#include <hip/hip_runtime.h>

#define NN 100000   // nodes
#define EE 1600000  // edges
#define BQ 65536    // queries
#define NBK 391     // node buckets of 256 (ceil(NN/256))
#define BINB 1024   // binning grid
#define ECH 1563    // edges per binning block (ceil(EE/BINB))

typedef __attribute__((ext_vector_type(8))) short short8;
typedef __attribute__((ext_vector_type(4))) float f32x4;
typedef __attribute__((ext_vector_type(2))) float f32x2;

__device__ __forceinline__ unsigned short bf16_rn(float f) {
    unsigned u = __builtin_bit_cast(unsigned, f);
    u += 0x7fff + ((u >> 16) & 1);
    return (unsigned short)(u >> 16);
}

// ---------------- fp8 e4m3 helpers (HW cvt with SW fallback) ------------------------

#if defined(__has_builtin)
#if __has_builtin(__builtin_amdgcn_cvt_pk_fp8_f32) && __has_builtin(__builtin_amdgcn_cvt_pk_f32_fp8)
#define HW_FP8 1
#endif
#endif
#ifndef HW_FP8
#define HW_FP8 0
#endif

__device__ __forceinline__ unsigned char sw_f32_to_e4m3(float f) {
    float a = fabsf(f);
    unsigned s = __builtin_bit_cast(unsigned, f) >> 31;
    if (!(a < 448.f)) return (unsigned char)((s << 7) | 0x7E);
    if (a < 0.015625f) {
        int q = (int)rintf(a * 512.0f);
        return (unsigned char)((s << 7) | q);
    }
    int e; float m = frexpf(a, &e);
    int q = (int)rintf(m * 16.0f);
    int exp = e - 1 + 7;
    if (q == 16) { q = 8; exp++; }
    if (exp >= 16 || (exp == 15 && q == 15)) return (unsigned char)((s << 7) | 0x7E);
    return (unsigned char)((s << 7) | (exp << 3) | (q - 8));
}
__device__ __forceinline__ float sw_e4m3_to_f32(unsigned char v) {
    unsigned s = v >> 7, e = (v >> 3) & 15, m = v & 7;
    float r = e ? ldexpf((float)(8 + m), (int)e - 10) : ldexpf((float)m, -9);
    return s ? -r : r;
}

__device__ __forceinline__ unsigned char f32_to_e4m3b(float f) {
#if HW_FP8
    return (unsigned char)(__builtin_amdgcn_cvt_pk_fp8_f32(f, f, 0, false) & 0xFF);
#else
    return sw_f32_to_e4m3(f);
#endif
}
__device__ __forceinline__ void unpack4_e4m3(unsigned v, float* o) {
#if HW_FP8
    f32x2 lo = __builtin_amdgcn_cvt_pk_f32_fp8((int)v, false);
    f32x2 hi = __builtin_amdgcn_cvt_pk_f32_fp8((int)v, true);
    o[0] = lo[0]; o[1] = lo[1]; o[2] = hi[0]; o[3] = hi[1];
#else
    o[0] = sw_e4m3_to_f32(v & 0xFF);
    o[1] = sw_e4m3_to_f32((v >> 8) & 0xFF);
    o[2] = sw_e4m3_to_f32((v >> 16) & 0xFF);
    o[3] = sw_e4m3_to_f32((v >> 24) & 0xFF);
#endif
}
// 8 fp8 -> 8 bf16 (exact)
__device__ __forceinline__ short8 fp8x8_to_bf16x8(uint2 u) {
    float f[8];
    unpack4_e4m3(u.x, f);
    unpack4_e4m3(u.y, f + 4);
    union { unsigned short s[8]; short8 v; } o;
#pragma unroll
    for (int i = 0; i < 8; i++) o.s[i] = bf16_rn(f[i]);
    return o.v;
}

// ---------------- bucket count / scan / bin / offsets / place -----------------------

__global__ __launch_bounds__(256) void k_bcount(const int* __restrict__ dst,
                                                int* __restrict__ bcnt) {
    __shared__ int h[NBK];
    int t = threadIdx.x, b = blockIdx.x;
    for (int j = t; j < NBK; j += 256) h[j] = 0;
    __syncthreads();
    int lo = b * ECH, hi = lo + ECH;
    if (hi > EE) hi = EE;
    for (int i = lo + t; i < hi; i += 256) atomicAdd(&h[dst[i] >> 8], 1);
    __syncthreads();
    for (int j = t; j < NBK; j += 256)
        if (h[j]) atomicAdd(&bcnt[j], h[j]);
}

__global__ __launch_bounds__(512) void k_bscan(const int* __restrict__ bcnt,
                                               int* __restrict__ bbase,
                                               int* __restrict__ bcur) {
    __shared__ int sd[512];
    int t = threadIdx.x;
    int v = (t < NBK) ? bcnt[t] : 0;
    sd[t] = v;
    __syncthreads();
    for (int o = 1; o < 512; o <<= 1) {
        int x = (t >= o) ? sd[t - o] : 0;
        __syncthreads();
        sd[t] += x;
        __syncthreads();
    }
    if (t < NBK) { int e = sd[t] - v; bbase[t] = e; bcur[t] = e; }
    if (t == 0) bbase[NBK] = EE;
}

__global__ __launch_bounds__(256) void k_bin(const int* __restrict__ src,
                                             const int* __restrict__ dst,
                                             int* __restrict__ bcur,
                                             int2* __restrict__ binned) {
    __shared__ int h[NBK];
    __shared__ int cur[NBK];
    int t = threadIdx.x, b = blockIdx.x;
    for (int j = t; j < NBK; j += 256) { h[j] = 0; cur[j] = 0; }
    __syncthreads();
    int lo = b * ECH, hi = lo + ECH;
    if (hi > EE) hi = EE;
    for (int i = lo + t; i < hi; i += 256) atomicAdd(&h[dst[i] >> 8], 1);
    __syncthreads();
    for (int j = t; j < NBK; j += 256)
        if (h[j]) h[j] = atomicAdd(&bcur[j], h[j]);
    __syncthreads();
    for (int i = lo + t; i < hi; i += 256) {
        int d = dst[i], bk = d >> 8;
        int pos = h[bk] + atomicAdd(&cur[bk], 1);
        binned[pos] = make_int2(src[i], d);
    }
}

__global__ __launch_bounds__(256) void k_boff(const int2* __restrict__ binned,
                                              const int* __restrict__ bbase,
                                              int* __restrict__ offsets,
                                              float* __restrict__ dinv) {
    __shared__ int lh[256];
    __shared__ int sd[256];
    int t = threadIdx.x, b = blockIdx.x;
    lh[t] = 0;
    __syncthreads();
    int lo = bbase[b], hi = bbase[b + 1];
    for (int i = lo + t; i < hi; i += 256) atomicAdd(&lh[binned[i].y & 255], 1);
    __syncthreads();
    int v = lh[t];
    sd[t] = v;
    __syncthreads();
    for (int o = 1; o < 256; o <<= 1) {
        int x = (t >= o) ? sd[t - o] : 0;
        __syncthreads();
        sd[t] += x;
        __syncthreads();
    }
    int node = (b << 8) + t;
    if (node < NN) {
        offsets[node] = lo + (sd[t] - v);
        dinv[node] = rsqrtf((float)v + 1.0f);
    }
    if (b == NBK - 1 && t == 0) offsets[NN] = EE;
}

__global__ __launch_bounds__(256) void k_place(const int2* __restrict__ binned,
                                               const int* __restrict__ bbase,
                                               const int* __restrict__ offsets,
                                               const float* __restrict__ dinv,
                                               int2* __restrict__ epair) {
    __shared__ int lcur[256];
    int t = threadIdx.x, b = blockIdx.x;
    int node = (b << 8) + t;
    lcur[t] = (node < NN) ? offsets[node] : 0;
    __syncthreads();
    int lo = bbase[b], hi = bbase[b + 1];
    for (int i = lo + t; i < hi; i += 256) {
        int2 e = binned[i];
        int pos = atomicAdd(&lcur[e.y & 255], 1);
        epair[pos] = make_int2(e.x, __builtin_bit_cast(int, dinv[e.x]));
    }
}

// ---------------- fused weight convert -> bf16 transposed ---------------------------

__global__ __launch_bounds__(256) void k_wtall(const float* __restrict__ W1,
                                               const float* __restrict__ W2,
                                               const float* __restrict__ W3,
                                               const float* __restrict__ Wf,
                                               const float* __restrict__ Wh1,
                                               const float* __restrict__ Wh2,
                                               const float* __restrict__ Wh3,
                                               unsigned short* __restrict__ Wt1,
                                               unsigned short* __restrict__ Wt2,
                                               unsigned short* __restrict__ Wt3,
                                               unsigned short* __restrict__ Wtf,
                                               unsigned short* __restrict__ Wth1,
                                               unsigned short* __restrict__ Wth2,
                                               unsigned short* __restrict__ Wth3) {
    int i = blockIdx.x * 256 + threadIdx.x;
    const float* W; unsigned short* Wt; int K, N, idx;
    if (i < 16384)       { W = W1;  Wt = Wt1;  K = 128; N = 128; idx = i; }
    else if (i < 32768)  { W = W2;  Wt = Wt2;  K = 128; N = 128; idx = i - 16384; }
    else if (i < 49152)  { W = W3;  Wt = Wt3;  K = 128; N = 128; idx = i - 32768; }
    else if (i < 65536)  { W = Wf;  Wt = Wtf;  K = 128; N = 128; idx = i - 49152; }
    else if (i < 131072) { W = Wh1; Wt = Wth1; K = 256; N = 256; idx = i - 65536; }
    else if (i < 163840) { W = Wh2; Wt = Wth2; K = 256; N = 128; idx = i - 131072; }
    else if (i < 172032) { W = Wh3; Wt = Wth3; K = 128; N = 64;  idx = i - 163840; }
    else return;
    int k = idx / N, n = idx % N;
    Wt[(size_t)n * K + k] = bf16_rn(W[idx]);
}

// ---------------- CC table: combined temporal+mode+bias contribution ----------------

__global__ __launch_bounds__(256) void k_cc(const float* __restrict__ day_table,
                                            const float* __restrict__ time_table,
                                            const float* __restrict__ mode_table,
                                            const float* __restrict__ Wf,
                                            const float* __restrict__ bf,
                                            const float* __restrict__ Wh1,
                                            const float* __restrict__ bh1,
                                            float* __restrict__ CC) {
    int c = blockIdx.x;                   // 0..29
    int mode = c % 3, dt = c / 3, time = dt % 5, day = dt / 5;
    __shared__ float temp[128];
    int t = threadIdx.x;
    if (t < 128) {
        float s = bf[t];
        for (int j = 0; j < 64; j++) s = fmaf(day_table[day * 64 + j],  Wf[j * 128 + t], s);
        for (int j = 0; j < 64; j++) s = fmaf(time_table[time * 64 + j], Wf[(64 + j) * 128 + t], s);
        temp[t] = fmaxf(s, 0.f);
    }
    __syncthreads();
    float s = bh1[t];
    for (int k = 0; k < 128; k++) s = fmaf(temp[k], Wh1[(size_t)(256 + k) * 256 + t], s);
    for (int j = 0; j < 64; j++)  s = fmaf(mode_table[mode * 64 + j], Wh1[(size_t)(384 + j) * 256 + t], s);
    CC[c * 256 + t] = s;
}

// ---------------- bf16 MFMA GEMM: C = A @ Wt^T (+bias)(+relu) -----------------------
// OUTM: 0=f32, 1=bf16, 2=fp8-e4m3. AMODE: 0=bf16, 1=f32, 2=fp8.

template <int K, int BN, int TN, int ACT, int OUTM, int AMODE>
__global__ __launch_bounds__(256) void k_mfma(const void* __restrict__ Ap,
                                              const unsigned short* __restrict__ Wt,
                                              const float* __restrict__ bias,
                                              void* __restrict__ Cp,
                                              int M, int Ntot) {
    constexpr int TM = 4;
    __shared__ unsigned short Al[128][72];
    __shared__ unsigned short Bl[BN][72];
    const int t = threadIdx.x;
    const int lane = t & 63, wave = t >> 6;
    const int ln = lane & 15, q8 = (lane >> 4) * 8;
    const int row0 = blockIdx.x * 128;
    const int col0 = blockIdx.y * BN;
    const int wm0 = (wave >> 1) * 64;
    const int wn0 = (wave & 1) * (TN * 16);
    f32x4 acc[TM][TN];
#pragma unroll
    for (int i = 0; i < TM; i++)
#pragma unroll
        for (int j = 0; j < TN; j++) acc[i][j] = (f32x4){0.f, 0.f, 0.f, 0.f};

    for (int k0 = 0; k0 < K; k0 += 64) {
#pragma unroll
        for (int it = 0; it < 4; it++) {
            int c = it * 256 + t;
            int r = c >> 3, cc = (c & 7) * 8;
            int grow = row0 + r;
            if (AMODE == 1) {
                const float* A = (const float*)Ap;
                union { unsigned short u[8]; short8 v; } tm8;
                if (grow < M) {
                    float4 v0 = *(const float4*)&A[(size_t)grow * K + k0 + cc];
                    float4 v1 = *(const float4*)&A[(size_t)grow * K + k0 + cc + 4];
                    tm8.u[0] = bf16_rn(v0.x); tm8.u[1] = bf16_rn(v0.y);
                    tm8.u[2] = bf16_rn(v0.z); tm8.u[3] = bf16_rn(v0.w);
                    tm8.u[4] = bf16_rn(v1.x); tm8.u[5] = bf16_rn(v1.y);
                    tm8.u[6] = bf16_rn(v1.z); tm8.u[7] = bf16_rn(v1.w);
                } else {
                    tm8.v = (short8){0, 0, 0, 0, 0, 0, 0, 0};
                }
                *(short8*)&Al[r][cc] = tm8.v;
            } else if (AMODE == 2) {
                const unsigned char* A = (const unsigned char*)Ap;
                short8 v = (short8){0, 0, 0, 0, 0, 0, 0, 0};
                if (grow < M) {
                    uint2 u = *(const uint2*)&A[(size_t)grow * K + k0 + cc];
                    v = fp8x8_to_bf16x8(u);
                }
                *(short8*)&Al[r][cc] = v;
            } else {
                const unsigned short* A = (const unsigned short*)Ap;
                short8 v = (short8){0, 0, 0, 0, 0, 0, 0, 0};
                if (grow < M) v = *(const short8*)&A[(size_t)grow * K + k0 + cc];
                *(short8*)&Al[r][cc] = v;
            }
        }
#pragma unroll
        for (int it = 0; it < BN / 32; it++) {
            int c = it * 256 + t;
            int r = c >> 3, cc = (c & 7) * 8;
            *(short8*)&Bl[r][cc] = *(const short8*)&Wt[(size_t)(col0 + r) * K + k0 + cc];
        }
        __syncthreads();
#pragma unroll
        for (int ks = 0; ks < 64; ks += 32) {
            short8 af[TM], bfr[TN];
#pragma unroll
            for (int i = 0; i < TM; i++)
                af[i] = *(const short8*)&Al[wm0 + i * 16 + ln][ks + q8];
#pragma unroll
            for (int j = 0; j < TN; j++)
                bfr[j] = *(const short8*)&Bl[wn0 + j * 16 + ln][ks + q8];
#pragma unroll
            for (int i = 0; i < TM; i++)
#pragma unroll
                for (int j = 0; j < TN; j++)
                    acc[i][j] = __builtin_amdgcn_mfma_f32_16x16x32_bf16(af[i], bfr[j], acc[i][j], 0, 0, 0);
        }
        __syncthreads();
    }
    const int qr = (lane >> 4) * 4;
#pragma unroll
    for (int i = 0; i < TM; i++) {
#pragma unroll
        for (int j = 0; j < TN; j++) {
            int col = col0 + wn0 + j * 16 + ln;
            float bv = bias ? bias[col] : 0.f;
#pragma unroll
            for (int r = 0; r < 4; r++) {
                int row = row0 + wm0 + i * 16 + qr + r;
                if (row < M) {
                    float v = acc[i][j][r] + bv;
                    if (ACT) v = fmaxf(v, 0.f);
                    if (OUTM == 1)      ((unsigned short*)Cp)[(size_t)row * Ntot + col] = bf16_rn(v);
                    else if (OUTM == 2) ((unsigned char*)Cp)[(size_t)row * Ntot + col] = f32_to_e4m3b(v);
                    else                ((float*)Cp)[(size_t)row * Ntot + col] = v;
                }
            }
        }
    }
}

// ---------------- head1: 64-row x 256-col tile, 256 thr, fp8 h gather ---------------

__global__ __launch_bounds__(256) void k_head1m(const unsigned char* __restrict__ hb,
                                                const int* __restrict__ orig,
                                                const int* __restrict__ dest,
                                                const int* __restrict__ day_ids,
                                                const int* __restrict__ time_ids,
                                                const int* __restrict__ mode_ids,
                                                const float* __restrict__ CC,
                                                const unsigned short* __restrict__ Wt,
                                                unsigned short* __restrict__ z1) {
    constexpr int TM = 4, TN = 4;
    __shared__ unsigned short Al[64][72];
    __shared__ unsigned short Bl[256][72];
    __shared__ int io[64], idd[64], cid[64];
    const int t = threadIdx.x;
    const int lane = t & 63, wave = t >> 6;
    const int ln = lane & 15, q8 = (lane >> 4) * 8;
    const int row0 = blockIdx.x * 64;
    const int wn0 = wave * 64;
    if (t < 64) {
        io[t] = orig[row0 + t];
        idd[t] = dest[row0 + t];
        cid[t] = (day_ids[row0 + t] * 5 + time_ids[row0 + t]) * 3 + mode_ids[row0 + t];
    }
    f32x4 acc[TM][TN];
#pragma unroll
    for (int i = 0; i < TM; i++)
#pragma unroll
        for (int j = 0; j < TN; j++) acc[i][j] = (f32x4){0.f, 0.f, 0.f, 0.f};
    __syncthreads();

    for (int k0 = 0; k0 < 256; k0 += 64) {
        const int* idsrc = (k0 < 128) ? io : idd;
        const int kb = k0 & 64;
#pragma unroll
        for (int it = 0; it < 2; it++) {
            int c = it * 256 + t;
            int r = c >> 3, cc = (c & 7) * 8;
            uint2 u = *(const uint2*)&hb[(size_t)idsrc[r] * 128 + kb + cc];
            *(short8*)&Al[r][cc] = fp8x8_to_bf16x8(u);
        }
#pragma unroll
        for (int it = 0; it < 8; it++) {
            int c = it * 256 + t;
            int r = c >> 3, cc = (c & 7) * 8;
            *(short8*)&Bl[r][cc] = *(const short8*)&Wt[(size_t)r * 256 + k0 + cc];
        }
        __syncthreads();
#pragma unroll
        for (int ks = 0; ks < 64; ks += 32) {
            short8 af[TM], bfr[TN];
#pragma unroll
            for (int i = 0; i < TM; i++)
                af[i] = *(const short8*)&Al[i * 16 + ln][ks + q8];
#pragma unroll
            for (int j = 0; j < TN; j++)
                bfr[j] = *(const short8*)&Bl[wn0 + j * 16 + ln][ks + q8];
#pragma unroll
            for (int i = 0; i < TM; i++)
#pragma unroll
                for (int j = 0; j < TN; j++)
                    acc[i][j] = __builtin_amdgcn_mfma_f32_16x16x32_bf16(af[i], bfr[j], acc[i][j], 0, 0, 0);
        }
        __syncthreads();
    }
    const int qr = (lane >> 4) * 4;
#pragma unroll
    for (int i = 0; i < TM; i++) {
#pragma unroll
        for (int j = 0; j < TN; j++) {
            int col = wn0 + j * 16 + ln;
#pragma unroll
            for (int r = 0; r < 4; r++) {
                int rl = i * 16 + qr + r;
                float v = acc[i][j][r] + CC[cid[rl] * 256 + col];
                z1[(size_t)(row0 + rl) * 256 + col] = bf16_rn(fmaxf(v, 0.f));
            }
        }
    }
}

// ---------------- edge aggregation (fp8 gather): wave = 8 nodes, 8 lanes/node -------

__global__ __launch_bounds__(256) void k_agg8(const unsigned char* __restrict__ hwp,
                                              const int2* __restrict__ epair,
                                              const int* __restrict__ offsets,
                                              const float* __restrict__ dinv,
                                              const float* __restrict__ bias,
                                              unsigned char* __restrict__ out) {
    const int wid = blockIdx.x * 4 + (threadIdx.x >> 6);
    const int lane = threadIdx.x & 63;
    const int g = lane >> 3, l = lane & 7;
    const int node = wid * 8 + g;
    if (node >= NN) return;
    float acc[16];
#pragma unroll
    for (int i = 0; i < 16; i++) acc[i] = 0.f;
    const int beg = offsets[node], end = offsets[node + 1];
    for (int e = beg; e < end; e += 8) {
        int2 p[8];
#pragma unroll
        for (int j = 0; j < 8; j++) {
            int ee = e + j;
            p[j] = epair[(ee < end) ? ee : (end - 1)];
        }
        uint4 v[8];
#pragma unroll
        for (int j = 0; j < 8; j++)
            v[j] = *(const uint4*)&hwp[(size_t)p[j].x * 128 + l * 16];
#pragma unroll
        for (int j = 0; j < 8; j++) {
            float c = (e + j < end) ? __builtin_bit_cast(float, p[j].y) : 0.f;
            float f[16];
            unpack4_e4m3(v[j].x, f + 0);
            unpack4_e4m3(v[j].y, f + 4);
            unpack4_e4m3(v[j].z, f + 8);
            unpack4_e4m3(v[j].w, f + 12);
#pragma unroll
            for (int i = 0; i < 16; i++) acc[i] = fmaf(f[i], c, acc[i]);
        }
    }
    float dd = dinv[node];
    uint4 sv = *(const uint4*)&hwp[(size_t)node * 128 + l * 16];
    float fs[16];
    unpack4_e4m3(sv.x, fs + 0);
    unpack4_e4m3(sv.y, fs + 4);
    unpack4_e4m3(sv.z, fs + 8);
    unpack4_e4m3(sv.w, fs + 12);
    float bb[16];
#pragma unroll
    for (int i = 0; i < 4; i++)
        *(float4*)&bb[4 * i] = *(const float4*)&bias[l * 16 + 4 * i];
    union { unsigned char b[16]; uint4 v; } o;
#pragma unroll
    for (int i = 0; i < 16; i++) {
        float s = fmaf(fs[i], dd, acc[i]);
        float v = fmaf(s, dd, bb[i]);
        o.b[i] = f32_to_e4m3b(fmaxf(v, 0.f));
    }
    *(uint4*)&out[(size_t)node * 128 + l * 16] = o.v;
}

// ---------------- fused head3+head4: out = sigmoid(relu(z2·Wh3+b3)·Wh4+b4) ----------

__global__ __launch_bounds__(256) void k_head34(const unsigned short* __restrict__ z2,
                                                const unsigned short* __restrict__ Wt3,
                                                const float* __restrict__ bh3,
                                                const float* __restrict__ Wh4,
                                                const float* __restrict__ bh4,
                                                float* __restrict__ out) {
    const int t = threadIdx.x;
    const int lane = t & 63, wave = t >> 6;
    const int ln = lane & 15, q8 = (lane >> 4) * 8;
    const int rowbase = blockIdx.x * 256 + wave * 64;
    f32x4 acc[4][4];
#pragma unroll
    for (int i = 0; i < 4; i++)
#pragma unroll
        for (int j = 0; j < 4; j++) acc[i][j] = (f32x4){0.f, 0.f, 0.f, 0.f};
#pragma unroll
    for (int ks = 0; ks < 128; ks += 32) {
        short8 af[4], bfr[4];
#pragma unroll
        for (int i = 0; i < 4; i++)
            af[i] = *(const short8*)&z2[(size_t)(rowbase + i * 16 + ln) * 128 + ks + q8];
#pragma unroll
        for (int j = 0; j < 4; j++)
            bfr[j] = *(const short8*)&Wt3[(size_t)(j * 16 + ln) * 128 + ks + q8];
#pragma unroll
        for (int i = 0; i < 4; i++)
#pragma unroll
            for (int j = 0; j < 4; j++)
                acc[i][j] = __builtin_amdgcn_mfma_f32_16x16x32_bf16(af[i], bfr[j], acc[i][j], 0, 0, 0);
    }
    const int qr = (lane >> 4) * 4;
    float b3c[4], w4c[4];
#pragma unroll
    for (int j = 0; j < 4; j++) {
        b3c[j] = bh3[j * 16 + ln];
        w4c[j] = Wh4[j * 16 + ln];
    }
    float b4 = bh4[0];
    float part[4][4];
#pragma unroll
    for (int i = 0; i < 4; i++)
#pragma unroll
        for (int r = 0; r < 4; r++) {
            float s = 0.f;
#pragma unroll
            for (int j = 0; j < 4; j++)
                s = fmaf(fmaxf(acc[i][j][r] + b3c[j], 0.f), w4c[j], s);
            part[i][r] = s;
        }
#pragma unroll
    for (int i = 0; i < 4; i++)
#pragma unroll
        for (int r = 0; r < 4; r++) {
            float s = part[i][r];
            s += __shfl_xor(s, 1); s += __shfl_xor(s, 2);
            s += __shfl_xor(s, 4); s += __shfl_xor(s, 8);
            part[i][r] = s;
        }
    if (ln == 0) {
#pragma unroll
        for (int i = 0; i < 4; i++)
#pragma unroll
            for (int r = 0; r < 4; r++)
                out[rowbase + i * 16 + qr + r] =
                    1.0f / (1.0f + expf(-(part[i][r] + b4)));
    }
}

// ---------------- launch ------------------------------------------------------------

extern "C" void kernel_launch(void* const* d_in, const int* in_sizes, int n_in,
                              void* d_out, int out_size, void* d_ws, size_t ws_size,
                              hipStream_t stream) {
    const float* x          = (const float*)d_in[0];
    const int*   eidx       = (const int*)d_in[1];
    const int*   esrc       = eidx;
    const int*   edst       = eidx + EE;
    const int*   origin     = (const int*)d_in[2];
    const int*   destid     = (const int*)d_in[3];
    const int*   day_ids    = (const int*)d_in[4];
    const int*   time_ids   = (const int*)d_in[5];
    const int*   mode_ids   = (const int*)d_in[6];
    const float* W1 = (const float*)d_in[7];   const float* b1 = (const float*)d_in[8];
    const float* W2 = (const float*)d_in[9];   const float* b2 = (const float*)d_in[10];
    const float* W3 = (const float*)d_in[11];  const float* b3 = (const float*)d_in[12];
    const float* day_table  = (const float*)d_in[13];
    const float* time_table = (const float*)d_in[14];
    const float* mode_table = (const float*)d_in[15];
    const float* Wf  = (const float*)d_in[16]; const float* bf  = (const float*)d_in[17];
    const float* Wh1 = (const float*)d_in[18]; const float* bh1 = (const float*)d_in[19];
    const float* Wh2 = (const float*)d_in[20]; const float* bh2 = (const float*)d_in[21];
    const float* Wh3 = (const float*)d_in[22]; const float* bh3 = (const float*)d_in[23];
    const float* Wh4 = (const float*)d_in[24]; const float* bh4 = (const float*)d_in[25];
    float* out = (float*)d_out;

    char* wsb = (char*)d_ws;
    size_t off = 0;
    auto alloc = [&](size_t bytes) -> char* {
        char* p = wsb + off;
        off = (off + bytes + 511) & ~(size_t)511;
        return p;
    };
    int*   bcnt    = (int*)alloc((NBK + 1) * 4);
    int*   bbase   = (int*)alloc((NBK + 1) * 4);
    int*   bcur    = (int*)alloc((NBK + 1) * 4);
    int*   offsets = (int*)alloc((size_t)(NN + 1) * 4);
    float* dinv    = (float*)alloc((size_t)NN * 4);
    int2*  binned  = (int2*)alloc((size_t)EE * 8);
    int2*  epair   = (int2*)alloc((size_t)EE * 8);
    unsigned short* Wt1  = (unsigned short*)alloc(128 * 128 * 2);
    unsigned short* Wt2  = (unsigned short*)alloc(128 * 128 * 2);
    unsigned short* Wt3  = (unsigned short*)alloc(128 * 128 * 2);
    unsigned short* Wtf  = (unsigned short*)alloc(128 * 128 * 2);
    unsigned short* Wth1 = (unsigned short*)alloc(256 * 256 * 2);
    unsigned short* Wth2 = (unsigned short*)alloc(128 * 256 * 2);
    unsigned short* Wth3 = (unsigned short*)alloc(64 * 128 * 2);
    float* CC = (float*)alloc(30 * 256 * 4);
    unsigned char*  bufHW = (unsigned char*)alloc((size_t)NN * 128);   // fp8 hw
    unsigned char*  bufH  = (unsigned char*)alloc((size_t)NN * 128);   // fp8 h
    unsigned short* z1 = (unsigned short*)alloc((size_t)BQ * 256 * 2);
    unsigned short* z2 = (unsigned short*)alloc((size_t)BQ * 128 * 2);

    hipMemsetAsync(bcnt, 0, (NBK + 1) * 4, stream);
    k_bcount<<<BINB, 256, 0, stream>>>(edst, bcnt);
    k_bscan<<<1, 512, 0, stream>>>(bcnt, bbase, bcur);
    k_bin<<<BINB, 256, 0, stream>>>(esrc, edst, bcur, binned);
    k_boff<<<NBK, 256, 0, stream>>>(binned, bbase, offsets, dinv);
    k_place<<<NBK, 256, 0, stream>>>(binned, bbase, offsets, dinv, epair);

    k_wtall<<<(172032 + 255) / 256, 256, 0, stream>>>(W1, W2, W3, Wf, Wh1, Wh2, Wh3,
                                                      Wt1, Wt2, Wt3, Wtf, Wth1, Wth2, Wth3);
    k_cc<<<30, 256, 0, stream>>>(day_table, time_table, mode_table, Wf, bf, Wh1, bh1, CC);

    const int GB = (NN + 127) / 128;   // 782
    const int AB = (NN + 31) / 32;     // 3125 blocks, 32 nodes/block
    k_mfma<128, 128, 4, 0, 2, 1><<<dim3(GB, 1), 256, 0, stream>>>(x, Wt1, nullptr, bufHW, NN, 128);
    k_agg8<<<AB, 256, 0, stream>>>(bufHW, epair, offsets, dinv, b1, bufH);
    k_mfma<128, 128, 4, 0, 2, 2><<<dim3(GB, 1), 256, 0, stream>>>(bufH, Wt2, nullptr, bufHW, NN, 128);
    k_agg8<<<AB, 256, 0, stream>>>(bufHW, epair, offsets, dinv, b2, bufH);
    k_mfma<128, 128, 4, 0, 2, 2><<<dim3(GB, 1), 256, 0, stream>>>(bufH, Wt3, nullptr, bufHW, NN, 128);
    k_agg8<<<AB, 256, 0, stream>>>(bufHW, epair, offsets, dinv, b3, bufH);
    // final h = bufH (fp8)

    k_head1m<<<BQ / 64, 256, 0, stream>>>(bufH, origin, destid, day_ids, time_ids,
                                          mode_ids, CC, Wth1, z1);
    k_mfma<256, 128, 4, 1, 1, 0><<<dim3(BQ / 128, 1), 256, 0, stream>>>(z1, Wth2, bh2, z2, BQ, 128);
    k_head34<<<BQ / 256, 256, 0, stream>>>(z2, Wth3, bh3, Wh4, bh4, out);
}

// Round 12
// 443.674 us; speedup vs baseline: 1.1008x; 1.1008x over previous
//
#include <hip/hip_runtime.h>

#define NN 100000   // nodes
#define EE 1600000  // edges
#define BQ 65536    // queries
#define NBK 391     // node buckets of 256 (ceil(NN/256))
#define BINB 256    // binning grid: 256 blocks keeps >=128B runs per (block,bucket)
#define ECH 6250    // edges per binning block (EE/BINB)

typedef __attribute__((ext_vector_type(8))) short short8;
typedef __attribute__((ext_vector_type(4))) float f32x4;
typedef __attribute__((ext_vector_type(2))) float f32x2;

__device__ __forceinline__ unsigned short bf16_rn(float f) {
    unsigned u = __builtin_bit_cast(unsigned, f);
    u += 0x7fff + ((u >> 16) & 1);
    return (unsigned short)(u >> 16);
}

// ---------------- fp8 e4m3 helpers (HW cvt with SW fallback) ------------------------

#if defined(__has_builtin)
#if __has_builtin(__builtin_amdgcn_cvt_pk_fp8_f32) && __has_builtin(__builtin_amdgcn_cvt_pk_f32_fp8)
#define HW_FP8 1
#endif
#endif
#ifndef HW_FP8
#define HW_FP8 0
#endif

__device__ __forceinline__ unsigned char sw_f32_to_e4m3(float f) {
    float a = fabsf(f);
    unsigned s = __builtin_bit_cast(unsigned, f) >> 31;
    if (!(a < 448.f)) return (unsigned char)((s << 7) | 0x7E);
    if (a < 0.015625f) {
        int q = (int)rintf(a * 512.0f);
        return (unsigned char)((s << 7) | q);
    }
    int e; float m = frexpf(a, &e);
    int q = (int)rintf(m * 16.0f);
    int exp = e - 1 + 7;
    if (q == 16) { q = 8; exp++; }
    if (exp >= 16 || (exp == 15 && q == 15)) return (unsigned char)((s << 7) | 0x7E);
    return (unsigned char)((s << 7) | (exp << 3) | (q - 8));
}
__device__ __forceinline__ float sw_e4m3_to_f32(unsigned char v) {
    unsigned s = v >> 7, e = (v >> 3) & 15, m = v & 7;
    float r = e ? ldexpf((float)(8 + m), (int)e - 10) : ldexpf((float)m, -9);
    return s ? -r : r;
}

__device__ __forceinline__ unsigned char f32_to_e4m3b(float f) {
#if HW_FP8
    return (unsigned char)(__builtin_amdgcn_cvt_pk_fp8_f32(f, f, 0, false) & 0xFF);
#else
    return sw_f32_to_e4m3(f);
#endif
}
__device__ __forceinline__ void unpack4_e4m3(unsigned v, float* o) {
#if HW_FP8
    f32x2 lo = __builtin_amdgcn_cvt_pk_f32_fp8((int)v, false);
    f32x2 hi = __builtin_amdgcn_cvt_pk_f32_fp8((int)v, true);
    o[0] = lo[0]; o[1] = lo[1]; o[2] = hi[0]; o[3] = hi[1];
#else
    o[0] = sw_e4m3_to_f32(v & 0xFF);
    o[1] = sw_e4m3_to_f32((v >> 8) & 0xFF);
    o[2] = sw_e4m3_to_f32((v >> 16) & 0xFF);
    o[3] = sw_e4m3_to_f32((v >> 24) & 0xFF);
#endif
}
// 8 fp8 -> 8 bf16 (exact)
__device__ __forceinline__ short8 fp8x8_to_bf16x8(uint2 u) {
    float f[8];
    unpack4_e4m3(u.x, f);
    unpack4_e4m3(u.y, f + 4);
    union { unsigned short s[8]; short8 v; } o;
#pragma unroll
    for (int i = 0; i < 8; i++) o.s[i] = bf16_rn(f[i]);
    return o.v;
}

// ---------------- bucket count / scan / bin / offsets / place -----------------------
// 1024-thread blocks: 16 waves/CU of MLP for the latency-bound scatter, while the
// 256-block partition keeps per-(block,bucket) runs >=128B (R11 lesson: more blocks
// fragments the write runs and doubles WRITE_SIZE).

__global__ __launch_bounds__(1024) void k_bcount(const int* __restrict__ dst,
                                                 int* __restrict__ bcnt) {
    __shared__ int h[NBK];
    int t = threadIdx.x, b = blockIdx.x;
    for (int j = t; j < NBK; j += 1024) h[j] = 0;
    __syncthreads();
    int lo = b * ECH, hi = lo + ECH;
    for (int i = lo + t; i < hi; i += 1024) atomicAdd(&h[dst[i] >> 8], 1);
    __syncthreads();
    for (int j = t; j < NBK; j += 1024)
        if (h[j]) atomicAdd(&bcnt[j], h[j]);
}

__global__ __launch_bounds__(512) void k_bscan(const int* __restrict__ bcnt,
                                               int* __restrict__ bbase,
                                               int* __restrict__ bcur) {
    __shared__ int sd[512];
    int t = threadIdx.x;
    int v = (t < NBK) ? bcnt[t] : 0;
    sd[t] = v;
    __syncthreads();
    for (int o = 1; o < 512; o <<= 1) {
        int x = (t >= o) ? sd[t - o] : 0;
        __syncthreads();
        sd[t] += x;
        __syncthreads();
    }
    if (t < NBK) { int e = sd[t] - v; bbase[t] = e; bcur[t] = e; }
    if (t == 0) bbase[NBK] = EE;
}

__global__ __launch_bounds__(1024) void k_bin(const int* __restrict__ src,
                                              const int* __restrict__ dst,
                                              int* __restrict__ bcur,
                                              int2* __restrict__ binned) {
    __shared__ int h[NBK];
    __shared__ int cur[NBK];
    int t = threadIdx.x, b = blockIdx.x;
    for (int j = t; j < NBK; j += 1024) { h[j] = 0; cur[j] = 0; }
    __syncthreads();
    int lo = b * ECH, hi = lo + ECH;
    for (int i = lo + t; i < hi; i += 1024) atomicAdd(&h[dst[i] >> 8], 1);
    __syncthreads();
    for (int j = t; j < NBK; j += 1024)
        if (h[j]) h[j] = atomicAdd(&bcur[j], h[j]);
    __syncthreads();
    for (int i = lo + t; i < hi; i += 1024) {
        int d = dst[i], bk = d >> 8;
        int pos = h[bk] + atomicAdd(&cur[bk], 1);
        binned[pos] = make_int2(src[i], d);
    }
}

__global__ __launch_bounds__(256) void k_boff(const int2* __restrict__ binned,
                                              const int* __restrict__ bbase,
                                              int* __restrict__ offsets,
                                              float* __restrict__ dinv) {
    __shared__ int lh[256];
    __shared__ int sd[256];
    int t = threadIdx.x, b = blockIdx.x;
    lh[t] = 0;
    __syncthreads();
    int lo = bbase[b], hi = bbase[b + 1];
    for (int i = lo + t; i < hi; i += 256) atomicAdd(&lh[binned[i].y & 255], 1);
    __syncthreads();
    int v = lh[t];
    sd[t] = v;
    __syncthreads();
    for (int o = 1; o < 256; o <<= 1) {
        int x = (t >= o) ? sd[t - o] : 0;
        __syncthreads();
        sd[t] += x;
        __syncthreads();
    }
    int node = (b << 8) + t;
    if (node < NN) {
        offsets[node] = lo + (sd[t] - v);
        dinv[node] = rsqrtf((float)v + 1.0f);
    }
    if (b == NBK - 1 && t == 0) offsets[NN] = EE;
}

__global__ __launch_bounds__(256) void k_place(const int2* __restrict__ binned,
                                               const int* __restrict__ bbase,
                                               const int* __restrict__ offsets,
                                               const float* __restrict__ dinv,
                                               int2* __restrict__ epair) {
    __shared__ int lcur[256];
    int t = threadIdx.x, b = blockIdx.x;
    int node = (b << 8) + t;
    lcur[t] = (node < NN) ? offsets[node] : 0;
    __syncthreads();
    int lo = bbase[b], hi = bbase[b + 1];
    for (int i = lo + t; i < hi; i += 256) {
        int2 e = binned[i];
        int pos = atomicAdd(&lcur[e.y & 255], 1);
        epair[pos] = make_int2(e.x, __builtin_bit_cast(int, dinv[e.x]));
    }
}

// ---------------- fused weight convert -> bf16 transposed ---------------------------

__global__ __launch_bounds__(256) void k_wtall(const float* __restrict__ W1,
                                               const float* __restrict__ W2,
                                               const float* __restrict__ W3,
                                               const float* __restrict__ Wf,
                                               const float* __restrict__ Wh1,
                                               const float* __restrict__ Wh2,
                                               const float* __restrict__ Wh3,
                                               unsigned short* __restrict__ Wt1,
                                               unsigned short* __restrict__ Wt2,
                                               unsigned short* __restrict__ Wt3,
                                               unsigned short* __restrict__ Wtf,
                                               unsigned short* __restrict__ Wth1,
                                               unsigned short* __restrict__ Wth2,
                                               unsigned short* __restrict__ Wth3) {
    int i = blockIdx.x * 256 + threadIdx.x;
    const float* W; unsigned short* Wt; int K, N, idx;
    if (i < 16384)       { W = W1;  Wt = Wt1;  K = 128; N = 128; idx = i; }
    else if (i < 32768)  { W = W2;  Wt = Wt2;  K = 128; N = 128; idx = i - 16384; }
    else if (i < 49152)  { W = W3;  Wt = Wt3;  K = 128; N = 128; idx = i - 32768; }
    else if (i < 65536)  { W = Wf;  Wt = Wtf;  K = 128; N = 128; idx = i - 49152; }
    else if (i < 131072) { W = Wh1; Wt = Wth1; K = 256; N = 256; idx = i - 65536; }
    else if (i < 163840) { W = Wh2; Wt = Wth2; K = 256; N = 128; idx = i - 131072; }
    else if (i < 172032) { W = Wh3; Wt = Wth3; K = 128; N = 64;  idx = i - 163840; }
    else return;
    int k = idx / N, n = idx % N;
    Wt[(size_t)n * K + k] = bf16_rn(W[idx]);
}

// ---------------- CC table: combined temporal+mode+bias contribution ----------------

__global__ __launch_bounds__(256) void k_cc(const float* __restrict__ day_table,
                                            const float* __restrict__ time_table,
                                            const float* __restrict__ mode_table,
                                            const float* __restrict__ Wf,
                                            const float* __restrict__ bf,
                                            const float* __restrict__ Wh1,
                                            const float* __restrict__ bh1,
                                            float* __restrict__ CC) {
    int c = blockIdx.x;                   // 0..29
    int mode = c % 3, dt = c / 3, time = dt % 5, day = dt / 5;
    __shared__ float temp[128];
    int t = threadIdx.x;
    if (t < 128) {
        float s = bf[t];
        for (int j = 0; j < 64; j++) s = fmaf(day_table[day * 64 + j],  Wf[j * 128 + t], s);
        for (int j = 0; j < 64; j++) s = fmaf(time_table[time * 64 + j], Wf[(64 + j) * 128 + t], s);
        temp[t] = fmaxf(s, 0.f);
    }
    __syncthreads();
    float s = bh1[t];
    for (int k = 0; k < 128; k++) s = fmaf(temp[k], Wh1[(size_t)(256 + k) * 256 + t], s);
    for (int j = 0; j < 64; j++)  s = fmaf(mode_table[mode * 64 + j], Wh1[(size_t)(384 + j) * 256 + t], s);
    CC[c * 256 + t] = s;
}

// ---------------- bf16 MFMA GEMM: C = A @ Wt^T (+bias)(+relu) -----------------------
// OUTM: 0=f32, 1=bf16, 2=fp8-e4m3. AMODE: 0=bf16, 1=f32, 2=fp8.

template <int K, int BN, int TN, int ACT, int OUTM, int AMODE>
__global__ __launch_bounds__(256) void k_mfma(const void* __restrict__ Ap,
                                              const unsigned short* __restrict__ Wt,
                                              const float* __restrict__ bias,
                                              void* __restrict__ Cp,
                                              int M, int Ntot) {
    constexpr int TM = 4;
    __shared__ unsigned short Al[128][72];
    __shared__ unsigned short Bl[BN][72];
    const int t = threadIdx.x;
    const int lane = t & 63, wave = t >> 6;
    const int ln = lane & 15, q8 = (lane >> 4) * 8;
    const int row0 = blockIdx.x * 128;
    const int col0 = blockIdx.y * BN;
    const int wm0 = (wave >> 1) * 64;
    const int wn0 = (wave & 1) * (TN * 16);
    f32x4 acc[TM][TN];
#pragma unroll
    for (int i = 0; i < TM; i++)
#pragma unroll
        for (int j = 0; j < TN; j++) acc[i][j] = (f32x4){0.f, 0.f, 0.f, 0.f};

    for (int k0 = 0; k0 < K; k0 += 64) {
#pragma unroll
        for (int it = 0; it < 4; it++) {
            int c = it * 256 + t;
            int r = c >> 3, cc = (c & 7) * 8;
            int grow = row0 + r;
            if (AMODE == 1) {
                const float* A = (const float*)Ap;
                union { unsigned short u[8]; short8 v; } tm8;
                if (grow < M) {
                    float4 v0 = *(const float4*)&A[(size_t)grow * K + k0 + cc];
                    float4 v1 = *(const float4*)&A[(size_t)grow * K + k0 + cc + 4];
                    tm8.u[0] = bf16_rn(v0.x); tm8.u[1] = bf16_rn(v0.y);
                    tm8.u[2] = bf16_rn(v0.z); tm8.u[3] = bf16_rn(v0.w);
                    tm8.u[4] = bf16_rn(v1.x); tm8.u[5] = bf16_rn(v1.y);
                    tm8.u[6] = bf16_rn(v1.z); tm8.u[7] = bf16_rn(v1.w);
                } else {
                    tm8.v = (short8){0, 0, 0, 0, 0, 0, 0, 0};
                }
                *(short8*)&Al[r][cc] = tm8.v;
            } else if (AMODE == 2) {
                const unsigned char* A = (const unsigned char*)Ap;
                short8 v = (short8){0, 0, 0, 0, 0, 0, 0, 0};
                if (grow < M) {
                    uint2 u = *(const uint2*)&A[(size_t)grow * K + k0 + cc];
                    v = fp8x8_to_bf16x8(u);
                }
                *(short8*)&Al[r][cc] = v;
            } else {
                const unsigned short* A = (const unsigned short*)Ap;
                short8 v = (short8){0, 0, 0, 0, 0, 0, 0, 0};
                if (grow < M) v = *(const short8*)&A[(size_t)grow * K + k0 + cc];
                *(short8*)&Al[r][cc] = v;
            }
        }
#pragma unroll
        for (int it = 0; it < BN / 32; it++) {
            int c = it * 256 + t;
            int r = c >> 3, cc = (c & 7) * 8;
            *(short8*)&Bl[r][cc] = *(const short8*)&Wt[(size_t)(col0 + r) * K + k0 + cc];
        }
        __syncthreads();
#pragma unroll
        for (int ks = 0; ks < 64; ks += 32) {
            short8 af[TM], bfr[TN];
#pragma unroll
            for (int i = 0; i < TM; i++)
                af[i] = *(const short8*)&Al[wm0 + i * 16 + ln][ks + q8];
#pragma unroll
            for (int j = 0; j < TN; j++)
                bfr[j] = *(const short8*)&Bl[wn0 + j * 16 + ln][ks + q8];
#pragma unroll
            for (int i = 0; i < TM; i++)
#pragma unroll
                for (int j = 0; j < TN; j++)
                    acc[i][j] = __builtin_amdgcn_mfma_f32_16x16x32_bf16(af[i], bfr[j], acc[i][j], 0, 0, 0);
        }
        __syncthreads();
    }
    const int qr = (lane >> 4) * 4;
#pragma unroll
    for (int i = 0; i < TM; i++) {
#pragma unroll
        for (int j = 0; j < TN; j++) {
            int col = col0 + wn0 + j * 16 + ln;
            float bv = bias ? bias[col] : 0.f;
#pragma unroll
            for (int r = 0; r < 4; r++) {
                int row = row0 + wm0 + i * 16 + qr + r;
                if (row < M) {
                    float v = acc[i][j][r] + bv;
                    if (ACT) v = fmaxf(v, 0.f);
                    if (OUTM == 1)      ((unsigned short*)Cp)[(size_t)row * Ntot + col] = bf16_rn(v);
                    else if (OUTM == 2) ((unsigned char*)Cp)[(size_t)row * Ntot + col] = f32_to_e4m3b(v);
                    else                ((float*)Cp)[(size_t)row * Ntot + col] = v;
                }
            }
        }
    }
}

// ---------------- head1: 64-row x 256-col tile, 256 thr, fp8 h gather ---------------

__global__ __launch_bounds__(256) void k_head1m(const unsigned char* __restrict__ hb,
                                                const int* __restrict__ orig,
                                                const int* __restrict__ dest,
                                                const int* __restrict__ day_ids,
                                                const int* __restrict__ time_ids,
                                                const int* __restrict__ mode_ids,
                                                const float* __restrict__ CC,
                                                const unsigned short* __restrict__ Wt,
                                                unsigned short* __restrict__ z1) {
    constexpr int TM = 4, TN = 4;
    __shared__ unsigned short Al[64][72];
    __shared__ unsigned short Bl[256][72];
    __shared__ int io[64], idd[64], cid[64];
    const int t = threadIdx.x;
    const int lane = t & 63, wave = t >> 6;
    const int ln = lane & 15, q8 = (lane >> 4) * 8;
    const int row0 = blockIdx.x * 64;
    const int wn0 = wave * 64;
    if (t < 64) {
        io[t] = orig[row0 + t];
        idd[t] = dest[row0 + t];
        cid[t] = (day_ids[row0 + t] * 5 + time_ids[row0 + t]) * 3 + mode_ids[row0 + t];
    }
    f32x4 acc[TM][TN];
#pragma unroll
    for (int i = 0; i < TM; i++)
#pragma unroll
        for (int j = 0; j < TN; j++) acc[i][j] = (f32x4){0.f, 0.f, 0.f, 0.f};
    __syncthreads();

    for (int k0 = 0; k0 < 256; k0 += 64) {
        const int* idsrc = (k0 < 128) ? io : idd;
        const int kb = k0 & 64;
#pragma unroll
        for (int it = 0; it < 2; it++) {
            int c = it * 256 + t;
            int r = c >> 3, cc = (c & 7) * 8;
            uint2 u = *(const uint2*)&hb[(size_t)idsrc[r] * 128 + kb + cc];
            *(short8*)&Al[r][cc] = fp8x8_to_bf16x8(u);
        }
#pragma unroll
        for (int it = 0; it < 8; it++) {
            int c = it * 256 + t;
            int r = c >> 3, cc = (c & 7) * 8;
            *(short8*)&Bl[r][cc] = *(const short8*)&Wt[(size_t)r * 256 + k0 + cc];
        }
        __syncthreads();
#pragma unroll
        for (int ks = 0; ks < 64; ks += 32) {
            short8 af[TM], bfr[TN];
#pragma unroll
            for (int i = 0; i < TM; i++)
                af[i] = *(const short8*)&Al[i * 16 + ln][ks + q8];
#pragma unroll
            for (int j = 0; j < TN; j++)
                bfr[j] = *(const short8*)&Bl[wn0 + j * 16 + ln][ks + q8];
#pragma unroll
            for (int i = 0; i < TM; i++)
#pragma unroll
                for (int j = 0; j < TN; j++)
                    acc[i][j] = __builtin_amdgcn_mfma_f32_16x16x32_bf16(af[i], bfr[j], acc[i][j], 0, 0, 0);
        }
        __syncthreads();
    }
    const int qr = (lane >> 4) * 4;
#pragma unroll
    for (int i = 0; i < TM; i++) {
#pragma unroll
        for (int j = 0; j < TN; j++) {
            int col = wn0 + j * 16 + ln;
#pragma unroll
            for (int r = 0; r < 4; r++) {
                int rl = i * 16 + qr + r;
                float v = acc[i][j][r] + CC[cid[rl] * 256 + col];
                z1[(size_t)(row0 + rl) * 256 + col] = bf16_rn(fmaxf(v, 0.f));
            }
        }
    }
}

// ---------------- edge aggregation (fp8 gather): wave = 8 nodes, 8 lanes/node -------

__global__ __launch_bounds__(256) void k_agg8(const unsigned char* __restrict__ hwp,
                                              const int2* __restrict__ epair,
                                              const int* __restrict__ offsets,
                                              const float* __restrict__ dinv,
                                              const float* __restrict__ bias,
                                              unsigned char* __restrict__ out) {
    const int wid = blockIdx.x * 4 + (threadIdx.x >> 6);
    const int lane = threadIdx.x & 63;
    const int g = lane >> 3, l = lane & 7;
    const int node = wid * 8 + g;
    if (node >= NN) return;
    float acc[16];
#pragma unroll
    for (int i = 0; i < 16; i++) acc[i] = 0.f;
    const int beg = offsets[node], end = offsets[node + 1];
    for (int e = beg; e < end; e += 8) {
        int2 p[8];
#pragma unroll
        for (int j = 0; j < 8; j++) {
            int ee = e + j;
            p[j] = epair[(ee < end) ? ee : (end - 1)];
        }
        uint4 v[8];
#pragma unroll
        for (int j = 0; j < 8; j++)
            v[j] = *(const uint4*)&hwp[(size_t)p[j].x * 128 + l * 16];
#pragma unroll
        for (int j = 0; j < 8; j++) {
            float c = (e + j < end) ? __builtin_bit_cast(float, p[j].y) : 0.f;
            float f[16];
            unpack4_e4m3(v[j].x, f + 0);
            unpack4_e4m3(v[j].y, f + 4);
            unpack4_e4m3(v[j].z, f + 8);
            unpack4_e4m3(v[j].w, f + 12);
#pragma unroll
            for (int i = 0; i < 16; i++) acc[i] = fmaf(f[i], c, acc[i]);
        }
    }
    float dd = dinv[node];
    uint4 sv = *(const uint4*)&hwp[(size_t)node * 128 + l * 16];
    float fs[16];
    unpack4_e4m3(sv.x, fs + 0);
    unpack4_e4m3(sv.y, fs + 4);
    unpack4_e4m3(sv.z, fs + 8);
    unpack4_e4m3(sv.w, fs + 12);
    float bb[16];
#pragma unroll
    for (int i = 0; i < 4; i++)
        *(float4*)&bb[4 * i] = *(const float4*)&bias[l * 16 + 4 * i];
    union { unsigned char b[16]; uint4 v; } o;
#pragma unroll
    for (int i = 0; i < 16; i++) {
        float s = fmaf(fs[i], dd, acc[i]);
        float v = fmaf(s, dd, bb[i]);
        o.b[i] = f32_to_e4m3b(fmaxf(v, 0.f));
    }
    *(uint4*)&out[(size_t)node * 128 + l * 16] = o.v;
}

// ---------------- fused head3+head4: out = sigmoid(relu(z2·Wh3+b3)·Wh4+b4) ----------

__global__ __launch_bounds__(256) void k_head34(const unsigned short* __restrict__ z2,
                                                const unsigned short* __restrict__ Wt3,
                                                const float* __restrict__ bh3,
                                                const float* __restrict__ Wh4,
                                                const float* __restrict__ bh4,
                                                float* __restrict__ out) {
    const int t = threadIdx.x;
    const int lane = t & 63, wave = t >> 6;
    const int ln = lane & 15, q8 = (lane >> 4) * 8;
    const int rowbase = blockIdx.x * 256 + wave * 64;
    f32x4 acc[4][4];
#pragma unroll
    for (int i = 0; i < 4; i++)
#pragma unroll
        for (int j = 0; j < 4; j++) acc[i][j] = (f32x4){0.f, 0.f, 0.f, 0.f};
#pragma unroll
    for (int ks = 0; ks < 128; ks += 32) {
        short8 af[4], bfr[4];
#pragma unroll
        for (int i = 0; i < 4; i++)
            af[i] = *(const short8*)&z2[(size_t)(rowbase + i * 16 + ln) * 128 + ks + q8];
#pragma unroll
        for (int j = 0; j < 4; j++)
            bfr[j] = *(const short8*)&Wt3[(size_t)(j * 16 + ln) * 128 + ks + q8];
#pragma unroll
        for (int i = 0; i < 4; i++)
#pragma unroll
            for (int j = 0; j < 4; j++)
                acc[i][j] = __builtin_amdgcn_mfma_f32_16x16x32_bf16(af[i], bfr[j], acc[i][j], 0, 0, 0);
    }
    const int qr = (lane >> 4) * 4;
    float b3c[4], w4c[4];
#pragma unroll
    for (int j = 0; j < 4; j++) {
        b3c[j] = bh3[j * 16 + ln];
        w4c[j] = Wh4[j * 16 + ln];
    }
    float b4 = bh4[0];
    float part[4][4];
#pragma unroll
    for (int i = 0; i < 4; i++)
#pragma unroll
        for (int r = 0; r < 4; r++) {
            float s = 0.f;
#pragma unroll
            for (int j = 0; j < 4; j++)
                s = fmaf(fmaxf(acc[i][j][r] + b3c[j], 0.f), w4c[j], s);
            part[i][r] = s;
        }
#pragma unroll
    for (int i = 0; i < 4; i++)
#pragma unroll
        for (int r = 0; r < 4; r++) {
            float s = part[i][r];
            s += __shfl_xor(s, 1); s += __shfl_xor(s, 2);
            s += __shfl_xor(s, 4); s += __shfl_xor(s, 8);
            part[i][r] = s;
        }
    if (ln == 0) {
#pragma unroll
        for (int i = 0; i < 4; i++)
#pragma unroll
            for (int r = 0; r < 4; r++)
                out[rowbase + i * 16 + qr + r] =
                    1.0f / (1.0f + expf(-(part[i][r] + b4)));
    }
}

// ---------------- launch ------------------------------------------------------------

extern "C" void kernel_launch(void* const* d_in, const int* in_sizes, int n_in,
                              void* d_out, int out_size, void* d_ws, size_t ws_size,
                              hipStream_t stream) {
    const float* x          = (const float*)d_in[0];
    const int*   eidx       = (const int*)d_in[1];
    const int*   esrc       = eidx;
    const int*   edst       = eidx + EE;
    const int*   origin     = (const int*)d_in[2];
    const int*   destid     = (const int*)d_in[3];
    const int*   day_ids    = (const int*)d_in[4];
    const int*   time_ids   = (const int*)d_in[5];
    const int*   mode_ids   = (const int*)d_in[6];
    const float* W1 = (const float*)d_in[7];   const float* b1 = (const float*)d_in[8];
    const float* W2 = (const float*)d_in[9];   const float* b2 = (const float*)d_in[10];
    const float* W3 = (const float*)d_in[11];  const float* b3 = (const float*)d_in[12];
    const float* day_table  = (const float*)d_in[13];
    const float* time_table = (const float*)d_in[14];
    const float* mode_table = (const float*)d_in[15];
    const float* Wf  = (const float*)d_in[16]; const float* bf  = (const float*)d_in[17];
    const float* Wh1 = (const float*)d_in[18]; const float* bh1 = (const float*)d_in[19];
    const float* Wh2 = (const float*)d_in[20]; const float* bh2 = (const float*)d_in[21];
    const float* Wh3 = (const float*)d_in[22]; const float* bh3 = (const float*)d_in[23];
    const float* Wh4 = (const float*)d_in[24]; const float* bh4 = (const float*)d_in[25];
    float* out = (float*)d_out;

    char* wsb = (char*)d_ws;
    size_t off = 0;
    auto alloc = [&](size_t bytes) -> char* {
        char* p = wsb + off;
        off = (off + bytes + 511) & ~(size_t)511;
        return p;
    };
    int*   bcnt    = (int*)alloc((NBK + 1) * 4);
    int*   bbase   = (int*)alloc((NBK + 1) * 4);
    int*   bcur    = (int*)alloc((NBK + 1) * 4);
    int*   offsets = (int*)alloc((size_t)(NN + 1) * 4);
    float* dinv    = (float*)alloc((size_t)NN * 4);
    int2*  binned  = (int2*)alloc((size_t)EE * 8);
    int2*  epair   = (int2*)alloc((size_t)EE * 8);
    unsigned short* Wt1  = (unsigned short*)alloc(128 * 128 * 2);
    unsigned short* Wt2  = (unsigned short*)alloc(128 * 128 * 2);
    unsigned short* Wt3  = (unsigned short*)alloc(128 * 128 * 2);
    unsigned short* Wtf  = (unsigned short*)alloc(128 * 128 * 2);
    unsigned short* Wth1 = (unsigned short*)alloc(256 * 256 * 2);
    unsigned short* Wth2 = (unsigned short*)alloc(128 * 256 * 2);
    unsigned short* Wth3 = (unsigned short*)alloc(64 * 128 * 2);
    float* CC = (float*)alloc(30 * 256 * 4);
    unsigned char*  bufHW = (unsigned char*)alloc((size_t)NN * 128);   // fp8 hw
    unsigned char*  bufH  = (unsigned char*)alloc((size_t)NN * 128);   // fp8 h
    unsigned short* z1 = (unsigned short*)alloc((size_t)BQ * 256 * 2);
    unsigned short* z2 = (unsigned short*)alloc((size_t)BQ * 128 * 2);

    hipMemsetAsync(bcnt, 0, (NBK + 1) * 4, stream);
    k_bcount<<<BINB, 1024, 0, stream>>>(edst, bcnt);
    k_bscan<<<1, 512, 0, stream>>>(bcnt, bbase, bcur);
    k_bin<<<BINB, 1024, 0, stream>>>(esrc, edst, bcur, binned);
    k_boff<<<NBK, 256, 0, stream>>>(binned, bbase, offsets, dinv);
    k_place<<<NBK, 256, 0, stream>>>(binned, bbase, offsets, dinv, epair);

    k_wtall<<<(172032 + 255) / 256, 256, 0, stream>>>(W1, W2, W3, Wf, Wh1, Wh2, Wh3,
                                                      Wt1, Wt2, Wt3, Wtf, Wth1, Wth2, Wth3);
    k_cc<<<30, 256, 0, stream>>>(day_table, time_table, mode_table, Wf, bf, Wh1, bh1, CC);

    const int GB = (NN + 127) / 128;   // 782
    const int AB = (NN + 31) / 32;     // 3125 blocks, 32 nodes/block
    k_mfma<128, 128, 4, 0, 2, 1><<<dim3(GB, 1), 256, 0, stream>>>(x, Wt1, nullptr, bufHW, NN, 128);
    k_agg8<<<AB, 256, 0, stream>>>(bufHW, epair, offsets, dinv, b1, bufH);
    k_mfma<128, 128, 4, 0, 2, 2><<<dim3(GB, 1), 256, 0, stream>>>(bufH, Wt2, nullptr, bufHW, NN, 128);
    k_agg8<<<AB, 256, 0, stream>>>(bufHW, epair, offsets, dinv, b2, bufH);
    k_mfma<128, 128, 4, 0, 2, 2><<<dim3(GB, 1), 256, 0, stream>>>(bufH, Wt3, nullptr, bufHW, NN, 128);
    k_agg8<<<AB, 256, 0, stream>>>(bufHW, epair, offsets, dinv, b3, bufH);
    // final h = bufH (fp8)

    k_head1m<<<BQ / 64, 256, 0, stream>>>(bufH, origin, destid, day_ids, time_ids,
                                          mode_ids, CC, Wth1, z1);
    k_mfma<256, 128, 4, 1, 1, 0><<<dim3(BQ / 128, 1), 256, 0, stream>>>(z1, Wth2, bh2, z2, BQ, 128);
    k_head34<<<BQ / 256, 256, 0, stream>>>(z2, Wth3, bh3, Wh4, bh4, out);
}